// Round 3
// baseline (692.960 us; speedup 1.0000x reference)
//
#include <hip/hip_runtime.h>
#include <hip/hip_bf16.h>

typedef short bf16x8 __attribute__((ext_vector_type(8)));
typedef float f32x4 __attribute__((ext_vector_type(4)));

#define HID 128
#define NRAD 6
#define TILE 64

static __device__ __forceinline__ unsigned short f2bf(float f) {
    union { float f; unsigned u; } v; v.f = f;
    unsigned r = v.u + 0x7FFFu + ((v.u >> 16) & 1u);
    return (unsigned short)(r >> 16);
}

static __device__ __forceinline__ float swishf(float z) {
    return z * __builtin_amdgcn_rcpf(1.0f + __expf(-z));
}

// ---------------------------------------------------------------------------
// Precompute: P1[v] = emb[v]@W1 + b_lin, P2[v] = emb[v]@W2, Wt = (W3^T) bf16
// ---------------------------------------------------------------------------
__global__ void precompute_kernel(const float* __restrict__ emb,
                                  const float* __restrict__ w_lin,
                                  const float* __restrict__ b_lin,
                                  float* __restrict__ P1,
                                  float* __restrict__ P2,
                                  unsigned short* __restrict__ Wt) {
    const int b = blockIdx.x;
    const int t = threadIdx.x; // 0..127 = output column n
    if (b < 190) {
        const int v = (b < 95) ? b : b - 95;
        const float* W = w_lin + (b < 95 ? 0 : HID * HID);
        float acc = (b < 95) ? b_lin[t] : 0.0f;
        #pragma unroll 4
        for (int k = 0; k < HID; ++k)
            acc = fmaf(emb[v * HID + k], W[k * HID + t], acc);
        (b < 95 ? P1 : P2)[v * HID + t] = acc;
    } else {
        const int kr = b - 190; // 0..127
        Wt[t * HID + kr] = f2bf(w_lin[(2 * HID + kr) * HID + t]);
    }
}

// ---------------------------------------------------------------------------
// Persistent edge kernel — LDS is READ-ONLY after one staging barrier.
// Each lane privately computes its MFMA B-fragment slice of
//   r = swish(rbf @ w_rbf + b_rbf)   (k = kk*32 + lg*8 .. +8 of edge w*16+lr)
// then  y = W3^T (A-op, LDS) x r (B-op, regs)  -> D: row=n, col=edge,
// and   out = swish(y + P1[x[i]] + P2[x[j]])   (float4 loads/stores).
// No LDS writes, no barriers in the loop -> race-free by construction.
// ---------------------------------------------------------------------------
__global__ __launch_bounds__(256, 4) void edge_kernel(
    const float* __restrict__ rbf, const int* __restrict__ ei,
    const int* __restrict__ ej, const int* __restrict__ x,
    const float* __restrict__ w_rbf, const float* __restrict__ b_rbf,
    const float* __restrict__ P1, const float* __restrict__ P2,
    const unsigned short* __restrict__ Wt,
    float* __restrict__ out, int E, int ntiles)
{
    __shared__ __align__(16) float s_w[7 * HID];             // rows 0..5: w_rbf, row 6: b_rbf
    __shared__ __align__(16) unsigned short sB[HID * HID];   // W3^T bf16, XOR-swizzled

    const int t = threadIdx.x;
    const int w = t >> 6, l = t & 63, lr = l & 15, lg = l >> 4;

    // ---- one-time read-only staging ----
    for (int idx = t; idx < NRAD * HID; idx += 256) s_w[idx] = w_rbf[idx];
    if (t < HID) s_w[6 * HID + t] = b_rbf[t];
    {
        const uint4* g = (const uint4*)Wt;
        #pragma unroll
        for (int q = 0; q < 8; ++q) {
            int gi = q * 256 + t;                 // coalesced
            int n = gi >> 4, cc = gi & 15;
            uint4 v = g[gi];
            *(uint4*)((char*)sB + n * 256 + ((cc * 16) ^ ((n & 7) << 4))) = v;
        }
    }
    __syncthreads();   // the ONLY barrier; LDS never written again

    const int n0base = lg * 8;

    for (int tile = blockIdx.x; tile < ntiles; tile += gridDim.x) {
        const int base = tile * TILE;
        const int e  = base + w * 16 + lr;       // this lane's edge (x4 lanes share it)
        const int ec = min(e, E - 1);

        // rbf row: 24 B, 8B-aligned; 4 sharing lanes hit the same cache line
        const float* rp = rbf + (size_t)ec * NRAD;
        const float2 r01 = *(const float2*)(rp);
        const float2 r23 = *(const float2*)(rp + 2);
        const float2 r45 = *(const float2*)(rp + 4);
        const int xi = x[ei[ec]];
        const int xj = x[ej[ec]];
        const float rv[NRAD] = { r01.x, r01.y, r23.x, r23.y, r45.x, r45.y };

        // ---- per-lane A (B-operand) fragments in registers ----
        bf16x8 af[4];
        #pragma unroll
        for (int kk = 0; kk < 4; ++kk) {
            const int n0 = kk * 32 + n0base;
            f32x4 z0 = *(const f32x4*)(s_w + 6 * HID + n0);
            f32x4 z1 = *(const f32x4*)(s_w + 6 * HID + n0 + 4);
            #pragma unroll
            for (int q = 0; q < NRAD; ++q) {
                const f32x4 w0 = *(const f32x4*)(s_w + q * HID + n0);
                const f32x4 w1 = *(const f32x4*)(s_w + q * HID + n0 + 4);
                #pragma unroll
                for (int u = 0; u < 4; ++u) {
                    z0[u] = fmaf(rv[q], w0[u], z0[u]);
                    z1[u] = fmaf(rv[q], w1[u], z1[u]);
                }
            }
            union { unsigned short s[8]; bf16x8 v; } pk;
            #pragma unroll
            for (int u = 0; u < 4; ++u) {
                pk.s[u]     = f2bf(swishf(z0[u]));
                pk.s[4 + u] = f2bf(swishf(z1[u]));
            }
            af[kk] = pk.v;
        }

        // ---- MFMA: D[row = n_local][col = edge_local] ----
        f32x4 acc[8];
        #pragma unroll
        for (int f = 0; f < 8; ++f) acc[f] = (f32x4){0.f, 0.f, 0.f, 0.f};

        #pragma unroll
        for (int kk = 0; kk < 4; ++kk) {
            const int colb = kk * 64 + lg * 16;
            #pragma unroll
            for (int f = 0; f < 8; ++f) {
                const int rowB = f * 16 + lr;
                bf16x8 bb = *(const bf16x8*)((const char*)sB +
                              rowB * 256 + (colb ^ ((rowB & 7) << 4)));
                acc[f] = __builtin_amdgcn_mfma_f32_16x16x32_bf16(bb, af[kk], acc[f], 0, 0, 0);
            }
        }

        // ---- epilogue: add gathered table rows, swish, float4 stores ----
        if (e < E) {
            const float* p1 = P1 + xi * HID;
            const float* p2 = P2 + xj * HID;
            float* op = out + (size_t)e * HID;
            #pragma unroll
            for (int f = 0; f < 8; ++f) {
                const int n0 = f * 16 + lg * 4;
                const f32x4 a1 = *(const f32x4*)(p1 + n0);
                const f32x4 a2 = *(const f32x4*)(p2 + n0);
                f32x4 v;
                #pragma unroll
                for (int u = 0; u < 4; ++u)
                    v[u] = swishf(acc[f][u] + a1[u] + a2[u]);
                *(f32x4*)(op + n0) = v;
            }
        }
    }
}

extern "C" void kernel_launch(void* const* d_in, const int* in_sizes, int n_in,
                              void* d_out, int out_size, void* d_ws, size_t ws_size,
                              hipStream_t stream) {
    const int*   x     = (const int*)  d_in[0];
    const float* rbf   = (const float*)d_in[1];
    const int*   ei    = (const int*)  d_in[2];
    const int*   ej    = (const int*)  d_in[3];
    const float* emb   = (const float*)d_in[4];
    const float* w_rbf = (const float*)d_in[5];
    const float* b_rbf = (const float*)d_in[6];
    const float* w_lin = (const float*)d_in[7];
    const float* b_lin = (const float*)d_in[8];
    float* out = (float*)d_out;
    const int E = in_sizes[2];

    // workspace: P1 (95*128 f32), P2, Wt (128x128 bf16)
    float* P1 = (float*)d_ws;
    float* P2 = (float*)((char*)d_ws + 49152);
    unsigned short* Wt = (unsigned short*)((char*)d_ws + 98304);

    hipLaunchKernelGGL(precompute_kernel, dim3(318), dim3(128), 0, stream,
                       emb, w_lin, b_lin, P1, P2, Wt);

    const int ntiles = (E + TILE - 1) / TILE;
    const int nblk = ntiles < 1024 ? ntiles : 1024;
    hipLaunchKernelGGL(edge_kernel, dim3(nblk), dim3(256), 0, stream,
                       rbf, ei, ej, x, w_rbf, b_rbf, P1, P2, Wt, out, E, ntiles);
}

// Round 4
// 341.952 us; speedup vs baseline: 2.0265x; 2.0265x over previous
//
#include <hip/hip_runtime.h>
#include <hip/hip_bf16.h>

typedef short bf16x8 __attribute__((ext_vector_type(8)));
typedef float f32x4 __attribute__((ext_vector_type(4)));

#define HID 128
#define NRAD 6
#define TILE 64

static __device__ __forceinline__ unsigned short f2bf(float f) {
    union { float f; unsigned u; } v; v.f = f;
    unsigned r = v.u + 0x7FFFu + ((v.u >> 16) & 1u);
    return (unsigned short)(r >> 16);
}

static __device__ __forceinline__ float swishf(float z) {
    return z * __builtin_amdgcn_rcpf(1.0f + __expf(-z));
}

// ---------------------------------------------------------------------------
// Precompute: P1[v] = emb[v]@W1 + b_lin, P2[v] = emb[v]@W2, Wt = (W3^T) bf16
// ---------------------------------------------------------------------------
__global__ void precompute_kernel(const float* __restrict__ emb,
                                  const float* __restrict__ w_lin,
                                  const float* __restrict__ b_lin,
                                  float* __restrict__ P1,
                                  float* __restrict__ P2,
                                  unsigned short* __restrict__ Wt) {
    const int b = blockIdx.x;
    const int t = threadIdx.x; // 0..127 = output column n
    if (b < 190) {
        const int v = (b < 95) ? b : b - 95;
        const float* W = w_lin + (b < 95 ? 0 : HID * HID);
        float acc = (b < 95) ? b_lin[t] : 0.0f;
        #pragma unroll 4
        for (int k = 0; k < HID; ++k)
            acc = fmaf(emb[v * HID + k], W[k * HID + t], acc);
        (b < 95 ? P1 : P2)[v * HID + t] = acc;
    } else {
        const int kr = b - 190; // 0..127
        Wt[t * HID + kr] = f2bf(w_lin[(2 * HID + kr) * HID + t]);
    }
}

// ---------------------------------------------------------------------------
// Persistent edge kernel — LDS is READ-ONLY after one staging barrier.
// Lane (lr,lg) of wave w privately computes r[edge w*16+lr][k=kk*32+lg*8..+8]
// in registers (its exact MFMA B-fragment), interleaved kk-by-kk with the
// MFMAs so only one fragment is live at a time (register-pressure fix).
//   y = W3^T (A-op, LDS) x r (B-op, regs) -> D: row=n, col=edge
//   out = swish(y + P1[x[i]] + P2[x[j]])
// No LDS writes, no barriers in the loop -> race-free by construction.
// ---------------------------------------------------------------------------
__global__ __launch_bounds__(256, 2) void edge_kernel(
    const float* __restrict__ rbf, const int* __restrict__ ei,
    const int* __restrict__ ej, const int* __restrict__ x,
    const float* __restrict__ w_rbf, const float* __restrict__ b_rbf,
    const float* __restrict__ P1, const float* __restrict__ P2,
    const unsigned short* __restrict__ Wt,
    float* __restrict__ out, int E, int ntiles)
{
    __shared__ __align__(16) float s_w[7 * HID];             // rows 0..5: w_rbf, row 6: b_rbf
    __shared__ __align__(16) unsigned short sB[HID * HID];   // W3^T bf16, XOR-swizzled

    const int t = threadIdx.x;
    const int w = t >> 6, l = t & 63, lr = l & 15, lg = l >> 4;

    // ---- one-time read-only staging ----
    for (int idx = t; idx < NRAD * HID; idx += 256) s_w[idx] = w_rbf[idx];
    if (t < HID) s_w[6 * HID + t] = b_rbf[t];
    {
        const uint4* g = (const uint4*)Wt;
        #pragma unroll
        for (int q = 0; q < 8; ++q) {
            int gi = q * 256 + t;                 // coalesced
            int n = gi >> 4, cc = gi & 15;
            uint4 v = g[gi];
            *(uint4*)((char*)sB + n * 256 + ((cc * 16) ^ ((n & 7) << 4))) = v;
        }
    }
    __syncthreads();   // the ONLY barrier; LDS never written again

    const int n0base = lg * 8;

    for (int tile = blockIdx.x; tile < ntiles; tile += gridDim.x) {
        const int base = tile * TILE;
        const int e  = base + w * 16 + lr;       // this lane's edge (x4 lanes share it)
        const int ec = min(e, E - 1);

        // rbf row: 24 B; the 4 sharing lanes hit the same cache lines
        const float* rp = rbf + (size_t)ec * NRAD;
        const float2 r01 = *(const float2*)(rp);
        const float2 r23 = *(const float2*)(rp + 2);
        const float2 r45 = *(const float2*)(rp + 4);
        const int xi = x[ei[ec]];
        const int xj = x[ej[ec]];
        const float r0 = r01.x, r1 = r01.y, r2 = r23.x,
                    r3 = r23.y, r4 = r45.x, r5 = r45.y;

        f32x4 acc[8];
        #pragma unroll
        for (int f = 0; f < 8; ++f) acc[f] = (f32x4){0.f, 0.f, 0.f, 0.f};

        // ---- kk-interleaved: build one B-fragment, feed 8 MFMAs ----
        #pragma unroll
        for (int kk = 0; kk < 4; ++kk) {
            const int n0 = kk * 32 + n0base;
            f32x4 z0 = *(const f32x4*)(s_w + 6 * HID + n0);
            f32x4 z1 = *(const f32x4*)(s_w + 6 * HID + n0 + 4);
            #define RSTEP(q, rq)                                           \
            {                                                              \
                const f32x4 w0 = *(const f32x4*)(s_w + (q) * HID + n0);    \
                const f32x4 w1 = *(const f32x4*)(s_w + (q) * HID + n0 + 4);\
                _Pragma("unroll")                                          \
                for (int u = 0; u < 4; ++u) {                              \
                    z0[u] = fmaf(rq, w0[u], z0[u]);                        \
                    z1[u] = fmaf(rq, w1[u], z1[u]);                        \
                }                                                          \
            }
            RSTEP(0, r0) RSTEP(1, r1) RSTEP(2, r2)
            RSTEP(3, r3) RSTEP(4, r4) RSTEP(5, r5)
            #undef RSTEP

            union { unsigned short s[8]; bf16x8 v; } pk;
            #pragma unroll
            for (int u = 0; u < 4; ++u) {
                pk.s[u]     = f2bf(swishf(z0[u]));
                pk.s[4 + u] = f2bf(swishf(z1[u]));
            }
            const bf16x8 af = pk.v;

            const int colb = kk * 64 + lg * 16;
            #pragma unroll
            for (int f = 0; f < 8; ++f) {
                const int rowB = f * 16 + lr;
                bf16x8 bb = *(const bf16x8*)((const char*)sB +
                              rowB * 256 + (colb ^ ((rowB & 7) << 4)));
                acc[f] = __builtin_amdgcn_mfma_f32_16x16x32_bf16(bb, af, acc[f], 0, 0, 0);
            }
        }

        // ---- epilogue: add gathered table rows, swish, float4 stores ----
        if (e < E) {
            const float* p1 = P1 + xi * HID;
            const float* p2 = P2 + xj * HID;
            float* op = out + (size_t)e * HID;
            #pragma unroll
            for (int f = 0; f < 8; ++f) {
                const int n0 = f * 16 + lg * 4;
                const f32x4 a1 = *(const f32x4*)(p1 + n0);
                const f32x4 a2 = *(const f32x4*)(p2 + n0);
                f32x4 v;
                #pragma unroll
                for (int u = 0; u < 4; ++u)
                    v[u] = swishf(acc[f][u] + a1[u] + a2[u]);
                *(f32x4*)(op + n0) = v;
            }
        }
    }
}

extern "C" void kernel_launch(void* const* d_in, const int* in_sizes, int n_in,
                              void* d_out, int out_size, void* d_ws, size_t ws_size,
                              hipStream_t stream) {
    const int*   x     = (const int*)  d_in[0];
    const float* rbf   = (const float*)d_in[1];
    const int*   ei    = (const int*)  d_in[2];
    const int*   ej    = (const int*)  d_in[3];
    const float* emb   = (const float*)d_in[4];
    const float* w_rbf = (const float*)d_in[5];
    const float* b_rbf = (const float*)d_in[6];
    const float* w_lin = (const float*)d_in[7];
    const float* b_lin = (const float*)d_in[8];
    float* out = (float*)d_out;
    const int E = in_sizes[2];

    // workspace: P1 (95*128 f32), P2, Wt (128x128 bf16)
    float* P1 = (float*)d_ws;
    float* P2 = (float*)((char*)d_ws + 49152);
    unsigned short* Wt = (unsigned short*)((char*)d_ws + 98304);

    hipLaunchKernelGGL(precompute_kernel, dim3(318), dim3(128), 0, stream,
                       emb, w_lin, b_lin, P1, P2, Wt);

    const int ntiles = (E + TILE - 1) / TILE;
    const int nblk = ntiles < 1024 ? ntiles : 1024;
    hipLaunchKernelGGL(edge_kernel, dim3(nblk), dim3(256), 0, stream,
                       rbf, ei, ej, x, w_rbf, b_rbf, P1, P2, Wt, out, E, ntiles);
}

// Round 5
// 161.003 us; speedup vs baseline: 4.3040x; 2.1239x over previous
//
#include <hip/hip_runtime.h>
#include <hip/hip_bf16.h>

typedef short bf16x8 __attribute__((ext_vector_type(8)));
typedef float f32x4 __attribute__((ext_vector_type(4)));

#define HID 128
#define NRAD 6
#define TILE 64

static __device__ __forceinline__ unsigned short f2bf(float f) {
    union { float f; unsigned u; } v; v.f = f;
    unsigned r = v.u + 0x7FFFu + ((v.u >> 16) & 1u);
    return (unsigned short)(r >> 16);
}

static __device__ __forceinline__ float swishf(float z) {
    return z * __builtin_amdgcn_rcpf(1.0f + __expf(-z));
}

// ---------------------------------------------------------------------------
// Precompute: P1[v] = emb[v]@W1 + b_lin, P2[v] = emb[v]@W2, Wt = (W3^T) bf16
// ---------------------------------------------------------------------------
__global__ void precompute_kernel(const float* __restrict__ emb,
                                  const float* __restrict__ w_lin,
                                  const float* __restrict__ b_lin,
                                  float* __restrict__ P1,
                                  float* __restrict__ P2,
                                  unsigned short* __restrict__ Wt) {
    const int b = blockIdx.x;
    const int t = threadIdx.x; // 0..127 = output column n
    if (b < 190) {
        const int v = (b < 95) ? b : b - 95;
        const float* W = w_lin + (b < 95 ? 0 : HID * HID);
        float acc = (b < 95) ? b_lin[t] : 0.0f;
        #pragma unroll 4
        for (int k = 0; k < HID; ++k)
            acc = fmaf(emb[v * HID + k], W[k * HID + t], acc);
        (b < 95 ? P1 : P2)[v * HID + t] = acc;
    } else {
        const int kr = b - 190; // 0..127
        Wt[t * HID + kr] = f2bf(w_lin[(2 * HID + kr) * HID + t]);
    }
}

// ---------------------------------------------------------------------------
// Persistent edge kernel — LDS READ-ONLY after one staging barrier.
// Lane (lr,lg) of wave w computes its private B-fragment slice of
//   r = swish(rbf @ w_rbf + b_rbf)  (edge w*16+lr, k = kk*32+lg*8..+8)
// then per n-fragment f: acc = sum_kk mfma(W3t_frag, r_frag) and the
// epilogue for that fragment immediately (minimal live registers).
// No LDS writes / barriers in the loop -> race-free by construction.
// ---------------------------------------------------------------------------
__global__ __launch_bounds__(256, 1) void edge_kernel(
    const float* __restrict__ rbf, const int* __restrict__ ei,
    const int* __restrict__ ej, const int* __restrict__ x,
    const float* __restrict__ w_rbf, const float* __restrict__ b_rbf,
    const float* __restrict__ P1, const float* __restrict__ P2,
    const unsigned short* __restrict__ Wt,
    float* __restrict__ out, int E, int ntiles)
{
    __shared__ __align__(16) float s_w[7 * HID];             // rows 0..5: w_rbf, row 6: b_rbf
    __shared__ __align__(16) unsigned short sB[HID * HID];   // W3^T bf16, XOR-swizzled

    const int t = threadIdx.x;
    const int w = t >> 6, l = t & 63, lr = l & 15, lg = l >> 4;

    // ---- one-time read-only staging ----
    for (int idx = t; idx < NRAD * HID; idx += 256) s_w[idx] = w_rbf[idx];
    if (t < HID) s_w[6 * HID + t] = b_rbf[t];
    {
        const uint4* g = (const uint4*)Wt;
        #pragma unroll
        for (int q = 0; q < 8; ++q) {
            int gi = q * 256 + t;                 // coalesced
            int n = gi >> 4, cc = gi & 15;
            uint4 v = g[gi];
            *(uint4*)((char*)sB + n * 256 + ((cc * 16) ^ ((n & 7) << 4))) = v;
        }
    }
    __syncthreads();   // the ONLY barrier; LDS never written again

    const int n0base = lg * 8;

    for (int tile = blockIdx.x; tile < ntiles; tile += gridDim.x) {
        const int base = tile * TILE;
        const int e  = base + w * 16 + lr;       // this lane's edge (x4 lanes share it)
        const int ec = min(e, E - 1);

        const float* rp = rbf + (size_t)ec * NRAD;
        const float2 r01 = *(const float2*)(rp);
        const float2 r23 = *(const float2*)(rp + 2);
        const float2 r45 = *(const float2*)(rp + 4);
        const int xi = x[ei[ec]];
        const int xj = x[ej[ec]];
        const float r0 = r01.x, r1 = r01.y, r2 = r23.x,
                    r3 = r23.y, r4 = r45.x, r5 = r45.y;

        // ---- build the 4 B-fragments (r slice) in registers ----
        bf16x8 af[4];
        #pragma unroll
        for (int kk = 0; kk < 4; ++kk) {
            const int n0 = kk * 32 + n0base;
            f32x4 z0 = *(const f32x4*)(s_w + 6 * HID + n0);
            f32x4 z1 = *(const f32x4*)(s_w + 6 * HID + n0 + 4);
            #define RSTEP(q, rq)                                           \
            {                                                              \
                const f32x4 w0 = *(const f32x4*)(s_w + (q) * HID + n0);    \
                const f32x4 w1 = *(const f32x4*)(s_w + (q) * HID + n0 + 4);\
                _Pragma("unroll")                                          \
                for (int u = 0; u < 4; ++u) {                              \
                    z0[u] = fmaf(rq, w0[u], z0[u]);                        \
                    z1[u] = fmaf(rq, w1[u], z1[u]);                        \
                }                                                          \
            }
            RSTEP(0, r0) RSTEP(1, r1) RSTEP(2, r2)
            RSTEP(3, r3) RSTEP(4, r4) RSTEP(5, r5)
            #undef RSTEP
            union { unsigned short s[8]; bf16x8 v; } pk;
            #pragma unroll
            for (int u = 0; u < 4; ++u) {
                pk.s[u]     = f2bf(swishf(z0[u]));
                pk.s[4 + u] = f2bf(swishf(z1[u]));
            }
            af[kk] = pk.v;
        }

        // ---- per-fragment MFMA + immediate epilogue (low live pressure) ----
        const bool valid = (e < E);
        const float* p1 = P1 + xi * HID;
        const float* p2 = P2 + xj * HID;
        float* op = out + (size_t)e * HID;

        #pragma unroll
        for (int f = 0; f < 8; ++f) {
            f32x4 acc = (f32x4){0.f, 0.f, 0.f, 0.f};
            const int rowB = f * 16 + lr;
            const int rB = rowB * 256, sw = (rowB & 7) << 4;
            #pragma unroll
            for (int kk = 0; kk < 4; ++kk) {
                const int colb = kk * 64 + lg * 16;
                bf16x8 bb = *(const bf16x8*)((const char*)sB + rB + (colb ^ sw));
                acc = __builtin_amdgcn_mfma_f32_16x16x32_bf16(bb, af[kk], acc, 0, 0, 0);
            }
            if (valid) {
                const int n0 = f * 16 + lg * 4;
                const f32x4 a1 = *(const f32x4*)(p1 + n0);
                const f32x4 a2 = *(const f32x4*)(p2 + n0);
                f32x4 v;
                #pragma unroll
                for (int u = 0; u < 4; ++u)
                    v[u] = swishf(acc[u] + a1[u] + a2[u]);
                *(f32x4*)(op + n0) = v;
            }
        }
    }
}

extern "C" void kernel_launch(void* const* d_in, const int* in_sizes, int n_in,
                              void* d_out, int out_size, void* d_ws, size_t ws_size,
                              hipStream_t stream) {
    const int*   x     = (const int*)  d_in[0];
    const float* rbf   = (const float*)d_in[1];
    const int*   ei    = (const int*)  d_in[2];
    const int*   ej    = (const int*)  d_in[3];
    const float* emb   = (const float*)d_in[4];
    const float* w_rbf = (const float*)d_in[5];
    const float* b_rbf = (const float*)d_in[6];
    const float* w_lin = (const float*)d_in[7];
    const float* b_lin = (const float*)d_in[8];
    float* out = (float*)d_out;
    const int E = in_sizes[2];

    // workspace: P1 (95*128 f32), P2, Wt (128x128 bf16)
    float* P1 = (float*)d_ws;
    float* P2 = (float*)((char*)d_ws + 49152);
    unsigned short* Wt = (unsigned short*)((char*)d_ws + 98304);

    hipLaunchKernelGGL(precompute_kernel, dim3(318), dim3(128), 0, stream,
                       emb, w_lin, b_lin, P1, P2, Wt);

    const int ntiles = (E + TILE - 1) / TILE;
    const int nblk = ntiles < 1024 ? ntiles : 1024;
    hipLaunchKernelGGL(edge_kernel, dim3(nblk), dim3(256), 0, stream,
                       rbf, ei, ej, x, w_rbf, b_rbf, P1, P2, Wt, out, E, ntiles);
}

// Round 6
// 134.076 us; speedup vs baseline: 5.1684x; 1.2008x over previous
//
#include <hip/hip_runtime.h>
#include <hip/hip_bf16.h>

typedef short bf16x8 __attribute__((ext_vector_type(8)));
typedef float f32x4 __attribute__((ext_vector_type(4)));

#define HID 128
#define NRAD 6
#define TILE 64

static __device__ __forceinline__ unsigned short f2bf(float f) {
    union { float f; unsigned u; } v; v.f = f;
    unsigned r = v.u + 0x7FFFu + ((v.u >> 16) & 1u);
    return (unsigned short)(r >> 16);
}

static __device__ __forceinline__ float swishf(float z) {
    return z * __builtin_amdgcn_rcpf(1.0f + __expf(-z));
}

// ---------------------------------------------------------------------------
// Precompute: P1[v] = emb[v]@W1 + b_lin, P2[v] = emb[v]@W2, Wt = (W3^T) bf16
// ---------------------------------------------------------------------------
__global__ void precompute_kernel(const float* __restrict__ emb,
                                  const float* __restrict__ w_lin,
                                  const float* __restrict__ b_lin,
                                  float* __restrict__ P1,
                                  float* __restrict__ P2,
                                  unsigned short* __restrict__ Wt) {
    const int b = blockIdx.x;
    const int t = threadIdx.x; // 0..127 = output column n
    if (b < 190) {
        const int v = (b < 95) ? b : b - 95;
        const float* W = w_lin + (b < 95 ? 0 : HID * HID);
        float acc = (b < 95) ? b_lin[t] : 0.0f;
        #pragma unroll 4
        for (int k = 0; k < HID; ++k)
            acc = fmaf(emb[v * HID + k], W[k * HID + t], acc);
        (b < 95 ? P1 : P2)[v * HID + t] = acc;
    } else {
        const int kr = b - 190; // 0..127
        Wt[t * HID + kr] = f2bf(w_lin[(2 * HID + kr) * HID + t]);
    }
}

// ---------------------------------------------------------------------------
// Persistent edge kernel — LDS READ-ONLY after one staging barrier.
// Software-pipelined: tile t+stride's rbf/ei/ej loads are issued while tile
// t computes; the x[] gather for tile t is issued at loop top and consumed
// ~1000 cycles later in the epilogue. Non-temporal output stores keep L2
// for the P1/P2/rbf streams.
// ---------------------------------------------------------------------------
__global__ __launch_bounds__(256, 1) void edge_kernel(
    const float* __restrict__ rbf, const int* __restrict__ ei,
    const int* __restrict__ ej, const int* __restrict__ x,
    const float* __restrict__ w_rbf, const float* __restrict__ b_rbf,
    const float* __restrict__ P1, const float* __restrict__ P2,
    const unsigned short* __restrict__ Wt,
    float* __restrict__ out, int E, int ntiles)
{
    __shared__ __align__(16) float s_w[7 * HID];             // rows 0..5: w_rbf, row 6: b_rbf
    __shared__ __align__(16) unsigned short sB[HID * HID];   // W3^T bf16, XOR-swizzled

    const int t = threadIdx.x;
    const int w = t >> 6, l = t & 63, lr = l & 15, lg = l >> 4;

    // ---- one-time read-only staging ----
    for (int idx = t; idx < NRAD * HID; idx += 256) s_w[idx] = w_rbf[idx];
    if (t < HID) s_w[6 * HID + t] = b_rbf[t];
    {
        const uint4* g = (const uint4*)Wt;
        #pragma unroll
        for (int q = 0; q < 8; ++q) {
            int gi = q * 256 + t;                 // coalesced
            int n = gi >> 4, cc = gi & 15;
            uint4 v = g[gi];
            *(uint4*)((char*)sB + n * 256 + ((cc * 16) ^ ((n & 7) << 4))) = v;
        }
    }
    __syncthreads();   // the ONLY barrier; LDS never written again

    const int n0base = lg * 8;
    const int elane = w * 16 + lr;               // lane's edge offset within tile

    int tile = blockIdx.x;

    // ---- pipeline preload: tile 0 inputs ----
    float2 r01, r23, r45;
    int ii, jj;
    {
        const int e0 = min(tile * TILE + elane, E - 1);
        const float* rp = rbf + (size_t)e0 * NRAD;
        r01 = *(const float2*)(rp);
        r23 = *(const float2*)(rp + 2);
        r45 = *(const float2*)(rp + 4);
        ii = ei[e0];
        jj = ej[e0];
    }

    for (; tile < ntiles; tile += gridDim.x) {
        const int e = tile * TILE + elane;

        // resolve current tile's x-gathers now (consumed in epilogue ~1000cy later)
        const int xi = x[ii];
        const int xj = x[jj];
        const float r0 = r01.x, r1 = r01.y, r2 = r23.x,
                    r3 = r23.y, r4 = r45.x, r5 = r45.y;

        // issue NEXT tile's streaming loads (hidden under this tile's compute)
        float2 n01, n23, n45;
        int ni, nj;
        {
            const int tn = tile + gridDim.x;
            const int en = min((tn < ntiles ? tn : tile) * TILE + elane, E - 1);
            const float* rp = rbf + (size_t)en * NRAD;
            n01 = *(const float2*)(rp);
            n23 = *(const float2*)(rp + 2);
            n45 = *(const float2*)(rp + 4);
            ni = ei[en];
            nj = ej[en];
        }

        // ---- build the 4 B-fragments (r slice) in registers ----
        bf16x8 af[4];
        #pragma unroll
        for (int kk = 0; kk < 4; ++kk) {
            const int n0 = kk * 32 + n0base;
            f32x4 z0 = *(const f32x4*)(s_w + 6 * HID + n0);
            f32x4 z1 = *(const f32x4*)(s_w + 6 * HID + n0 + 4);
            #define RSTEP(q, rq)                                           \
            {                                                              \
                const f32x4 w0 = *(const f32x4*)(s_w + (q) * HID + n0);    \
                const f32x4 w1 = *(const f32x4*)(s_w + (q) * HID + n0 + 4);\
                _Pragma("unroll")                                          \
                for (int u = 0; u < 4; ++u) {                              \
                    z0[u] = fmaf(rq, w0[u], z0[u]);                        \
                    z1[u] = fmaf(rq, w1[u], z1[u]);                        \
                }                                                          \
            }
            RSTEP(0, r0) RSTEP(1, r1) RSTEP(2, r2)
            RSTEP(3, r3) RSTEP(4, r4) RSTEP(5, r5)
            #undef RSTEP
            union { unsigned short s[8]; bf16x8 v; } pk;
            #pragma unroll
            for (int u = 0; u < 4; ++u) {
                pk.s[u]     = f2bf(swishf(z0[u]));
                pk.s[4 + u] = f2bf(swishf(z1[u]));
            }
            af[kk] = pk.v;
        }

        // ---- per-fragment MFMA + immediate epilogue ----
        const bool valid = (e < E);
        const float* p1 = P1 + xi * HID;
        const float* p2 = P2 + xj * HID;
        float* op = out + (size_t)e * HID;

        #pragma unroll
        for (int f = 0; f < 8; ++f) {
            f32x4 acc = (f32x4){0.f, 0.f, 0.f, 0.f};
            const int rowB = f * 16 + lr;
            const int rB = rowB * 256, sw = (rowB & 7) << 4;
            #pragma unroll
            for (int kk = 0; kk < 4; ++kk) {
                const int colb = kk * 64 + lg * 16;
                bf16x8 bb = *(const bf16x8*)((const char*)sB + rB + (colb ^ sw));
                acc = __builtin_amdgcn_mfma_f32_16x16x32_bf16(bb, af[kk], acc, 0, 0, 0);
            }
            if (valid) {
                const int n0 = f * 16 + lg * 4;
                const f32x4 a1 = *(const f32x4*)(p1 + n0);
                const f32x4 a2 = *(const f32x4*)(p2 + n0);
                f32x4 v;
                #pragma unroll
                for (int u = 0; u < 4; ++u)
                    v[u] = swishf(acc[u] + a1[u] + a2[u]);
                __builtin_nontemporal_store(v, (f32x4*)(op + n0));
            }
        }

        // rotate pipeline registers
        r01 = n01; r23 = n23; r45 = n45; ii = ni; jj = nj;
    }
}

extern "C" void kernel_launch(void* const* d_in, const int* in_sizes, int n_in,
                              void* d_out, int out_size, void* d_ws, size_t ws_size,
                              hipStream_t stream) {
    const int*   x     = (const int*)  d_in[0];
    const float* rbf   = (const float*)d_in[1];
    const int*   ei    = (const int*)  d_in[2];
    const int*   ej    = (const int*)  d_in[3];
    const float* emb   = (const float*)d_in[4];
    const float* w_rbf = (const float*)d_in[5];
    const float* b_rbf = (const float*)d_in[6];
    const float* w_lin = (const float*)d_in[7];
    const float* b_lin = (const float*)d_in[8];
    float* out = (float*)d_out;
    const int E = in_sizes[2];

    // workspace: P1 (95*128 f32), P2, Wt (128x128 bf16)
    float* P1 = (float*)d_ws;
    float* P2 = (float*)((char*)d_ws + 49152);
    unsigned short* Wt = (unsigned short*)((char*)d_ws + 98304);

    hipLaunchKernelGGL(precompute_kernel, dim3(318), dim3(128), 0, stream,
                       emb, w_lin, b_lin, P1, P2, Wt);

    const int ntiles = (E + TILE - 1) / TILE;
    const int nblk = ntiles < 1024 ? ntiles : 1024;
    hipLaunchKernelGGL(edge_kernel, dim3(nblk), dim3(256), 0, stream,
                       rbf, ei, ej, x, w_rbf, b_rbf, P1, P2, Wt, out, E, ntiles);
}